// Round 4
// baseline (342.546 us; speedup 1.0000x reference)
//
#include <hip/hip_runtime.h>
#include <stdint.h>

#define BATCH 4
#define SEQ   2048
#define NHEAD 16
#define DHEAD 64
#define HID   1024

typedef __bf16 bf16x8 __attribute__((ext_vector_type(8)));
typedef __bf16 bf16x4 __attribute__((ext_vector_type(4)));
typedef float  f32x4  __attribute__((ext_vector_type(4)));

// load 8 contiguous f32, round to bf16x8
__device__ __forceinline__ bf16x8 load8f(const float* p) {
  const f32x4 a = ((const f32x4*)p)[0];
  const f32x4 b = ((const f32x4*)p)[1];
  bf16x8 r;
#pragma unroll
  for (int i = 0; i < 4; ++i) r[i] = (__bf16)a[i];
#pragma unroll
  for (int i = 0; i < 4; ++i) r[4 + i] = (__bf16)b[i];
  return r;
}

// async global->LDS, 16B per lane. LDS dest = wave-uniform base + lane*16.
__device__ __forceinline__ void gload_lds16(const __bf16* g, __bf16* l) {
  __builtin_amdgcn_global_load_lds(
      (const __attribute__((address_space(1))) uint32_t*)g,
      (__attribute__((address_space(3))) uint32_t*)l,
      16, 0, 0);
}

// ---------------------------------------------------------------------------
// fused f32 -> bf16 conversion: x (1048576 units) + Wq/Wk/Wv (131072 each)
// in ONE launch. 8 elements/thread.  (r3 win: -6 us launch overhead)
// ---------------------------------------------------------------------------
#define XUNITS 1048576
#define WUNITS 131072

__global__ __launch_bounds__(256) void cvt_fused_kernel(
    const float* __restrict__ x,
    const float* __restrict__ Wq, const float* __restrict__ Wk,
    const float* __restrict__ Wv,
    __bf16* __restrict__ xb, __bf16* __restrict__ Wb) {
  const int i = blockIdx.x * 256 + threadIdx.x;
  const float* s;
  __bf16* d;
  if (i < XUNITS) {
    s = x + (size_t)i * 8;
    d = xb + (size_t)i * 8;
  } else {
    const int j = i - XUNITS;
    const int w = j >> 17;          // /131072
    const int o = j & (WUNITS - 1);
    s = (w == 0 ? Wq : w == 1 ? Wk : Wv) + (size_t)o * 8;
    d = Wb + ((size_t)w << 20) + (size_t)o * 8;
  }
  *(bf16x8*)d = load8f(s);
}

#define ASTRIDE 40
#define BK 32

// ---------------------------------------------------------------------------
// qkv: m97-exact geometry. 256 threads / 4 waves; wave w covers m-rows
// [wr*64,+64) x n-cols [wc*64,+64) (wr=w>>1, wc=w&1) -> 4x4 fragments,
// 16 MFMA : 8 ds_read_b128 per wave per K-step (was 8:6 -- the r1/r2 null).
// Single-buffer 2-barrier K-loop, gload_lds w=16, linear [128][32] LDS.
// Q (+RoPE) -> d_out f32; K (+RoPE) -> Kws[B,H,S,DH]; V^T -> Vws[B,H,DH,S].
// ---------------------------------------------------------------------------
__global__ __launch_bounds__(256) void qkv_bf16_kernel(
    const __bf16* __restrict__ xb, const __bf16* __restrict__ Wb,
    const float* __restrict__ bq, const float* __restrict__ bk,
    const float* __restrict__ bv, const float* __restrict__ sp,
    float* __restrict__ qout, __bf16* __restrict__ Kws, __bf16* __restrict__ Vws)
{
  const int widx = blockIdx.z;
  const __bf16* __restrict__ W    = Wb + (size_t)widx * HID * HID;
  const float*  __restrict__ bias = (widx == 0) ? bq : (widx == 1) ? bk : bv;

  const int m0   = blockIdx.y * 128;
  const int n0   = blockIdx.x * 128;
  const int tid  = threadIdx.x;
  const int lane = tid & 63;
  const int quad = lane >> 4;
  const int l16  = lane & 15;
  const int wave = tid >> 6;          // 0..3
  const int wr   = wave >> 1, wc = wave & 1;

  __shared__ __align__(16) __bf16 As[128 * BK];   // [row][k], linear, 8 KB
  __shared__ __align__(16) __bf16 Bs[128 * BK];

  // staging: round r covers rows [r*64,+64); thread -> row r*64+(tid>>2),
  // 16B chunk (tid&3). LDS dest = wave-uniform base + lane*16B (linear match).
  const int srow = tid >> 2;          // 0..63
  const int scb  = tid & 3;
  const __bf16* aglb0 = xb + (size_t)(m0 + srow) * HID + scb * 8;
  const __bf16* aglb1 = xb + (size_t)(m0 + 64 + srow) * HID + scb * 8;
  const __bf16* bglb0 = W  + (size_t)(n0 + srow) * HID + scb * 8;
  const __bf16* bglb1 = W  + (size_t)(n0 + 64 + srow) * HID + scb * 8;
  __bf16* alds0 = As + wave * 512;          // + lane*16B by HW
  __bf16* alds1 = As + 2048 + wave * 512;
  __bf16* blds0 = Bs + wave * 512;
  __bf16* blds1 = Bs + 2048 + wave * 512;

  f32x4 acc[4][4];
  const f32x4 z = {0.f, 0.f, 0.f, 0.f};
#pragma unroll
  for (int i = 0; i < 4; ++i)
#pragma unroll
    for (int j = 0; j < 4; ++j) acc[i][j] = z;

#pragma unroll 1
  for (int k0 = 0; k0 < HID; k0 += BK) {
    gload_lds16(aglb0 + k0, alds0);
    gload_lds16(aglb1 + k0, alds1);
    gload_lds16(bglb0 + k0, blds0);
    gload_lds16(bglb1 + k0, blds1);
    __syncthreads();                  // drains vmcnt -> tiles ready

    bf16x8 af[4], bfr[4];
#pragma unroll
    for (int mt = 0; mt < 4; ++mt)
      af[mt] = *(const bf16x8*)(As + (wr * 64 + mt * 16 + l16) * BK + quad * 8);
#pragma unroll
    for (int nt = 0; nt < 4; ++nt)
      bfr[nt] = *(const bf16x8*)(Bs + (wc * 64 + nt * 16 + l16) * BK + quad * 8);

    if (widx < 2) {
#pragma unroll
      for (int mt = 0; mt < 4; ++mt)
#pragma unroll
        for (int nt = 0; nt < 4; ++nt)
          acc[mt][nt] = __builtin_amdgcn_mfma_f32_16x16x32_bf16(af[mt], bfr[nt], acc[mt][nt], 0, 0, 0);
    } else {
      // swapped operands -> V^T output
#pragma unroll
      for (int mt = 0; mt < 4; ++mt)
#pragma unroll
        for (int nt = 0; nt < 4; ++nt)
          acc[mt][nt] = __builtin_amdgcn_mfma_f32_16x16x32_bf16(bfr[nt], af[mt], acc[mt][nt], 0, 0, 0);
    }
    __syncthreads();                  // reads done before next stage
  }

  if (widx < 2) {
#pragma unroll
    for (int mt = 0; mt < 4; ++mt) {
#pragma unroll
      for (int nt = 0; nt < 4; ++nt) {
        const int n = n0 + wc * 64 + nt * 16 + l16;
        const int h = n >> 6, d = n & 63;
        const float bval = bias[n];
#pragma unroll
        for (int v = 0; v < 4; ++v) {
          const int m = m0 + wr * 64 + mt * 16 + quad * 4 + v;
          const int b = m >> 11, s = m & (SEQ - 1);
          float val = acc[mt][nt][v] + bval;
          // RoPE pairs (2j,2j+1) sit in adjacent lanes (d parity = lane bit 0)
          float p  = __shfl_xor(val, 1);
          float sn = sp[s * 64 + (d >> 1)];
          float cs = sp[s * 64 + 32 + (d >> 1)];
          val = val * cs + ((d & 1) ? p : -p) * sn;
          if (widx == 0) {
            qout[((size_t)b * SEQ + s) * HID + n] = val;
          } else {
            Kws[(((size_t)b * NHEAD + h) * SEQ + s) * DHEAD + d] = (__bf16)val;
          }
        }
      }
    }
  } else {
#pragma unroll
    for (int mt = 0; mt < 4; ++mt) {
#pragma unroll
      for (int nt = 0; nt < 4; ++nt) {
        const int m = m0 + wr * 64 + mt * 16 + l16;   // X-row from l16 (swapped)
        const int b = m >> 11, s = m & (SEQ - 1);
#pragma unroll
        for (int v = 0; v < 4; ++v) {
          const int n = n0 + wc * 64 + nt * 16 + quad * 4 + v;
          const int h = n >> 6, d = n & 63;
          float val = acc[mt][nt][v] + bias[n];
          Vws[(((size_t)b * NHEAD + h) * DHEAD + d) * SEQ + s] = (__bf16)val;
        }
      }
    }
  }
}

// ---------------------------------------------------------------------------
// qkv fallback (ws too small): f32 inputs, 512-thread version. (unchanged)
// ---------------------------------------------------------------------------
__global__ __launch_bounds__(512) void qkv_f32_kernel(
    const float* __restrict__ x,
    const float* __restrict__ Wq, const float* __restrict__ bq,
    const float* __restrict__ Wk, const float* __restrict__ bk,
    const float* __restrict__ Wv, const float* __restrict__ bv,
    const float* __restrict__ sp,
    float* __restrict__ qout, __bf16* __restrict__ Kws, __bf16* __restrict__ Vws)
{
  const int widx = blockIdx.z;
  const float* __restrict__ W    = (widx == 0) ? Wq : (widx == 1) ? Wk : Wv;
  const float* __restrict__ bias = (widx == 0) ? bq : (widx == 1) ? bk : bv;

  const int m0   = blockIdx.y * 128;
  const int n0   = blockIdx.x * 128;
  const int tid  = threadIdx.x;
  const int lane = tid & 63;
  const int quad = lane >> 4;
  const int l16  = lane & 15;
  const int wave = tid >> 6;
  const int wr   = wave >> 1, wc = wave & 1;

  __shared__ __align__(16) __bf16 As[128 * ASTRIDE];
  __shared__ __align__(16) __bf16 Bs[128 * ASTRIDE];

  const int srow = tid >> 2;
  const int scb  = tid & 3;

  f32x4 acc[2][4];
  const f32x4 z = {0.f, 0.f, 0.f, 0.f};
#pragma unroll
  for (int i = 0; i < 2; ++i)
#pragma unroll
    for (int j = 0; j < 4; ++j) acc[i][j] = z;

  bf16x8 areg = load8f(x + (size_t)(m0 + srow) * HID + scb * 8);
  bf16x8 breg = load8f(W + (size_t)(n0 + srow) * HID + scb * 8);

  for (int k0 = 0; k0 < HID; k0 += 32) {
    __syncthreads();
    *(bf16x8*)(As + srow * ASTRIDE + scb * 8) = areg;
    *(bf16x8*)(Bs + srow * ASTRIDE + scb * 8) = breg;
    __syncthreads();

    if (k0 + 32 < HID) {
      areg = load8f(x + (size_t)(m0 + srow) * HID + (k0 + 32) + scb * 8);
      breg = load8f(W + (size_t)(n0 + srow) * HID + (k0 + 32) + scb * 8);
    }

    bf16x8 af[2], bfr[4];
#pragma unroll
    for (int mt = 0; mt < 2; ++mt)
      af[mt] = *(const bf16x8*)(As + (wr * 32 + mt * 16 + l16) * ASTRIDE + quad * 8);
#pragma unroll
    for (int nt = 0; nt < 4; ++nt)
      bfr[nt] = *(const bf16x8*)(Bs + (wc * 64 + nt * 16 + l16) * ASTRIDE + quad * 8);

    if (widx < 2) {
#pragma unroll
      for (int mt = 0; mt < 2; ++mt)
#pragma unroll
        for (int nt = 0; nt < 4; ++nt)
          acc[mt][nt] = __builtin_amdgcn_mfma_f32_16x16x32_bf16(af[mt], bfr[nt], acc[mt][nt], 0, 0, 0);
    } else {
#pragma unroll
      for (int mt = 0; mt < 2; ++mt)
#pragma unroll
        for (int nt = 0; nt < 4; ++nt)
          acc[mt][nt] = __builtin_amdgcn_mfma_f32_16x16x32_bf16(bfr[nt], af[mt], acc[mt][nt], 0, 0, 0);
    }
  }

  if (widx < 2) {
#pragma unroll
    for (int mt = 0; mt < 2; ++mt) {
#pragma unroll
      for (int nt = 0; nt < 4; ++nt) {
        const int n = n0 + wc * 64 + nt * 16 + l16;
        const int h = n >> 6, d = n & 63;
        const float bval = bias[n];
#pragma unroll
        for (int v = 0; v < 4; ++v) {
          const int m = m0 + wr * 32 + mt * 16 + quad * 4 + v;
          const int b = m >> 11, s = m & (SEQ - 1);
          float val = acc[mt][nt][v] + bval;
          float p  = __shfl_xor(val, 1);
          float sn = sp[s * 64 + (d >> 1)];
          float cs = sp[s * 64 + 32 + (d >> 1)];
          val = val * cs + ((d & 1) ? p : -p) * sn;
          if (widx == 0) {
            qout[((size_t)b * SEQ + s) * HID + n] = val;
          } else {
            Kws[(((size_t)b * NHEAD + h) * SEQ + s) * DHEAD + d] = (__bf16)val;
          }
        }
      }
    }
  } else {
#pragma unroll
    for (int mt = 0; mt < 2; ++mt) {
#pragma unroll
      for (int nt = 0; nt < 4; ++nt) {
        const int m = m0 + wr * 32 + mt * 16 + l16;
        const int b = m >> 11, s = m & (SEQ - 1);
#pragma unroll
        for (int v = 0; v < 4; ++v) {
          const int n = n0 + wc * 64 + nt * 16 + quad * 4 + v;
          const int h = n >> 6, d = n & 63;
          float val = acc[mt][nt][v] + bias[n];
          Vws[(((size_t)b * NHEAD + h) * DHEAD + d) * SEQ + s] = (__bf16)val;
        }
      }
    }
  }
}

// ---------------------------------------------------------------------------
// attn: 256 threads / 4 waves; wave w owns q-rows [w*32,+32) (TWO 16-row
// fragments) of the 128-row Q tile. Every kf/vf LDS fragment now feeds 2
// MFMAs (was 1) -> per-CU DS-pipe cycles -33% (attn is LDS-pipe-bound:
// r3 evidence -- barriers/occupancy null, DS-cycle model matches 142 us).
// Single-buffer staging, 2 barriers/tile (r2-proven). setprio kept.
// ---------------------------------------------------------------------------
#define KT 64
#define QSTR 72
#define LOG2E 1.44269504088896340736f
#define PSHIFT 12.0f

__global__ __launch_bounds__(256) void attn_kernel(
    float* __restrict__ qo,
    const __bf16* __restrict__ Kws, const __bf16* __restrict__ Vws,
    const float* __restrict__ mask)
{
  const int q0   = blockIdx.x * 128;
  const int bh   = blockIdx.y;
  const int b    = bh >> 4, h = bh & 15;
  const int tid  = threadIdx.x;
  const int lane = tid & 63;
  const int wave = tid >> 6;          // 0..3
  const int quad = lane >> 4;
  const int l16  = lane & 15;

  __shared__ __align__(16) __bf16 Ks[64 * QSTR];    // [t][k]
  __shared__ __align__(16) __bf16 Vts[64 * QSTR];   // [d][t]
  __shared__ __align__(16) __bf16 PS[128 * QSTR];   // [q][t]

  const __bf16* kbase = Kws + (size_t)bh * SEQ * DHEAD;
  const __bf16* vbase = Vws + (size_t)bh * DHEAD * SEQ;

  // ---- Q fragments (B-operand): q-row = wave*32 + mq*16 + l16 ----
  bf16x8 qf[2][2];
#pragma unroll
  for (int mq = 0; mq < 2; ++mq)
#pragma unroll
    for (int ks = 0; ks < 2; ++ks)
      qf[mq][ks] = load8f(qo + ((size_t)b * SEQ + q0 + wave * 32 + mq * 16 + l16) * HID
                             + h * DHEAD + ks * 32 + quad * 8);

  f32x4 o_acc[2][4];   // [mq][dblk], C-layout: d=quad*4+v, q=l16
  const f32x4 z = {0.f, 0.f, 0.f, 0.f};
#pragma unroll
  for (int mq = 0; mq < 2; ++mq)
#pragma unroll
    for (int i = 0; i < 4; ++i) o_acc[mq][i] = z;
  float l_part[2] = {0.f, 0.f};

  // staging: 256 threads, thread -> row tid>>2 (0..63), two 16B chunks
  const int qrow = tid >> 2;          // 0..63
  const int qcb  = tid & 3;           // 16-elem col block
  bf16x8 krg0 = *(const bf16x8*)(kbase + (size_t)qrow * DHEAD + qcb * 16);
  bf16x8 krg1 = *(const bf16x8*)(kbase + (size_t)qrow * DHEAD + qcb * 16 + 8);
  bf16x8 vrg0 = *(const bf16x8*)(vbase + (size_t)qrow * SEQ + qcb * 16);
  bf16x8 vrg1 = *(const bf16x8*)(vbase + (size_t)qrow * SEQ + qcb * 16 + 8);

  const float SC2 = 0.125f * LOG2E;

  for (int t0 = 0; t0 < SEQ; t0 += KT) {
    *(bf16x8*)(Ks  + qrow * QSTR + qcb * 16)     = krg0;
    *(bf16x8*)(Ks  + qrow * QSTR + qcb * 16 + 8) = krg1;
    *(bf16x8*)(Vts + qrow * QSTR + qcb * 16)     = vrg0;
    *(bf16x8*)(Vts + qrow * QSTR + qcb * 16 + 8) = vrg1;
    __syncthreads();

    if (t0 + KT < SEQ) {
      krg0 = *(const bf16x8*)(kbase + (size_t)(t0 + KT + qrow) * DHEAD + qcb * 16);
      krg1 = *(const bf16x8*)(kbase + (size_t)(t0 + KT + qrow) * DHEAD + qcb * 16 + 8);
      vrg0 = *(const bf16x8*)(vbase + (size_t)qrow * SEQ + (t0 + KT) + qcb * 16);
      vrg1 = *(const bf16x8*)(vbase + (size_t)qrow * SEQ + (t0 + KT) + qcb * 16 + 8);
    }

    // ---- S^T: sc[mq][nt]: t-rows nt*16+quad*4+v, q-col = l16 ----
    f32x4 sc[2][4];
#pragma unroll
    for (int mq = 0; mq < 2; ++mq)
#pragma unroll
      for (int nt = 0; nt < 4; ++nt) sc[mq][nt] = z;

    __builtin_amdgcn_s_setprio(1);
#pragma unroll
    for (int ks = 0; ks < 2; ++ks) {
      bf16x8 kf[4];
#pragma unroll
      for (int nt = 0; nt < 4; ++nt)
        kf[nt] = *(const bf16x8*)(Ks + (nt * 16 + l16) * QSTR + ks * 32 + quad * 8);
#pragma unroll
      for (int mq = 0; mq < 2; ++mq)
#pragma unroll
        for (int nt = 0; nt < 4; ++nt)
          sc[mq][nt] = __builtin_amdgcn_mfma_f32_16x16x32_bf16(kf[nt], qf[mq][ks], sc[mq][nt], 0, 0, 0);
    }
    __builtin_amdgcn_s_setprio(0);

    // mask for t = t0 + nt*16 + quad*4 + v (same for both mq)
    f32x4 mv4[4];
#pragma unroll
    for (int nt = 0; nt < 4; ++nt)
      mv4[nt] = *(const f32x4*)(mask + b * SEQ + t0 + nt * 16 + quad * 4);

    // ---- shifted softmax numerators; b64-packed PS writes ----
#pragma unroll
    for (int mq = 0; mq < 2; ++mq) {
      const int prow = wave * 32 + mq * 16 + l16;
#pragma unroll
      for (int nt = 0; nt < 4; ++nt) {
        bf16x4 pk;
#pragma unroll
        for (int v = 0; v < 4; ++v) {
          const float p = __builtin_amdgcn_exp2f(sc[mq][nt][v] * SC2 + mv4[nt][v] * LOG2E - PSHIFT);
          l_part[mq] += p;
          pk[v] = (__bf16)p;
        }
        *(bf16x4*)(PS + prow * QSTR + nt * 16 + quad * 4) = pk;
      }
    }
    // no barrier: PS rows are wave-private (same-wave DS ops in order)

    // ---- O^T += Vt . P^T : A=Vt[d][t], B=PS[q][t] ----
    __builtin_amdgcn_s_setprio(1);
#pragma unroll
    for (int ks2 = 0; ks2 < 2; ++ks2) {
      bf16x8 vf[4], pf[2];
#pragma unroll
      for (int db = 0; db < 4; ++db)
        vf[db] = *(const bf16x8*)(Vts + (db * 16 + l16) * QSTR + ks2 * 32 + quad * 8);
#pragma unroll
      for (int mq = 0; mq < 2; ++mq)
        pf[mq] = *(const bf16x8*)(PS + (wave * 32 + mq * 16 + l16) * QSTR + ks2 * 32 + quad * 8);
#pragma unroll
      for (int mq = 0; mq < 2; ++mq)
#pragma unroll
        for (int db = 0; db < 4; ++db)
          o_acc[mq][db] = __builtin_amdgcn_mfma_f32_16x16x32_bf16(vf[db], pf[mq], o_acc[mq][db], 0, 0, 0);
    }
    __builtin_amdgcn_s_setprio(0);
    __syncthreads();   // Ks/Vts reads done before next staging store
  }

  // ---- epilogue per mq: quad-reduce l, normalize, f32x4 stores ----
#pragma unroll
  for (int mq = 0; mq < 2; ++mq) {
    float l = l_part[mq];
    l += __shfl_xor(l, 16);
    l += __shfl_xor(l, 32);
    const float inv = 1.0f / l;
    const int s = q0 + wave * 32 + mq * 16 + l16;
    float* op = qo + ((size_t)b * SEQ + s) * HID + h * DHEAD + quad * 4;
#pragma unroll
    for (int db = 0; db < 4; ++db) {
      f32x4 val = o_acc[mq][db];
      val[0] *= inv; val[1] *= inv; val[2] *= inv; val[3] *= inv;
      *(f32x4*)(op + db * 16) = val;
    }
  }
}

// ---------------------------------------------------------------------------
extern "C" void kernel_launch(void* const* d_in, const int* in_sizes, int n_in,
                              void* d_out, int out_size, void* d_ws, size_t ws_size,
                              hipStream_t stream) {
  const float* x    = (const float*)d_in[0];
  const float* mask = (const float*)d_in[1];
  const float* sp   = (const float*)d_in[2];
  const float* Wq   = (const float*)d_in[3];
  const float* bq   = (const float*)d_in[4];
  const float* Wk   = (const float*)d_in[5];
  const float* bk   = (const float*)d_in[6];
  const float* Wv   = (const float*)d_in[7];
  const float* bv   = (const float*)d_in[8];
  float* out = (float*)d_out;

  const size_t per = (size_t)BATCH * NHEAD * SEQ * DHEAD;  // 8388608
  const size_t wel = (size_t)3 * HID * HID;                // 3145728
  __bf16* Kws = (__bf16*)d_ws;
  __bf16* Vws = Kws + per;

  // pre-convert path needs K + V + x_bf16 + W_bf16 = 56.6 MB (fits: proven r6)
  const size_t need = (2 * per + per + wel) * sizeof(__bf16);
  if (ws_size >= need) {
    __bf16* xb = Vws + per;
    __bf16* Wb = xb + per;
    // one fused cvt launch: (1048576 + 3*131072) units / 256 = 5632 blocks
    cvt_fused_kernel<<<5632, 256, 0, stream>>>(x, Wq, Wk, Wv, xb, Wb);
    qkv_bf16_kernel<<<dim3(8, 64, 3), 256, 0, stream>>>(
        xb, Wb, bq, bk, bv, sp, out, Kws, Vws);
  } else {
    qkv_f32_kernel<<<dim3(8, 64, 3), 512, 0, stream>>>(
        x, Wq, bq, Wk, bk, Wv, bv, sp, out, Kws, Vws);
  }
  attn_kernel<<<dim3(16, 64), 256, 0, stream>>>(out, Kws, Vws, mask);
}